// Round 3
// baseline (58.429 us; speedup 1.0000x reference)
//
#include <hip/hip_runtime.h>

// Per-channel histogram: in [LENGTH=1e6, C=64] int32 values in [0,256),
// out [64, 256] int32 counts. Memory-bound: 256 MB read -> ~41 us floor.
//
// R3: latency-hiding push. 2 blocks/CU (512 blocks, 128 KB LDS/CU,
// launch_bounds forces <=64 VGPR -> 32 waves/CU) + 4x unrolled main loop
// issuing 8 dwordx4 (512 B/wave) with clamped addresses before any LDS
// atomic. In-flight/CU: 32 waves * 512 B = 16 KB > 9.2 KB needed to cover
// ~900cy HBM latency at 6.3 TB/s.

#define NCH   64
#define NBINS 256
#define HIST_SIZE (NCH * NBINS)   // 16384 ints = 64 KB LDS
#define NQWORDS   (HIST_SIZE / 2) // 8192 packed pairs
#define THREADS 1024
#define BLOCKS  512               // 2 blocks/CU

__global__ __launch_bounds__(THREADS, 8) void hist_kernel(
    const int* __restrict__ in, unsigned long long* __restrict__ out, long long n8)
{
    __shared__ int hist[HIST_SIZE];
    const int tid = threadIdx.x;

    #pragma unroll
    for (int k = 0; k < HIST_SIZE / THREADS; ++k)
        hist[tid + k * THREADS] = 0;
    __syncthreads();

    const int4* __restrict__ in4 = (const int4*)in;
    const long long stride = (long long)BLOCKS * THREADS;      // divisible by 8
    const long long gid = (long long)blockIdx.x * THREADS + tid;

    // Chunk i covers flat indices [8i,8i+8) -> channels (i&7)*8..+7.
    // stride % 8 == 0 -> channel base is per-thread invariant.
    const int c0 = (int)((gid & 7) << 3);
    int* __restrict__ h = &hist[c0 * NBINS];

    const long long nm1 = n8 - 1;
    for (long long i = gid; i < n8; i += 4 * stride) {
        const long long i1 = i + stride, i2 = i + 2 * stride, i3 = i + 3 * stride;
        // Clamp so all 8 loads issue unconditionally (batched in flight).
        const long long j1 = i1 < n8 ? i1 : nm1;
        const long long j2 = i2 < n8 ? i2 : nm1;
        const long long j3 = i3 < n8 ? i3 : nm1;
        int4 a0 = in4[2 * i];  int4 b0 = in4[2 * i + 1];
        int4 a1 = in4[2 * j1]; int4 b1 = in4[2 * j1 + 1];
        int4 a2 = in4[2 * j2]; int4 b2 = in4[2 * j2 + 1];
        int4 a3 = in4[2 * j3]; int4 b3 = in4[2 * j3 + 1];

        atomicAdd(&h[0 * NBINS + a0.x], 1); atomicAdd(&h[1 * NBINS + a0.y], 1);
        atomicAdd(&h[2 * NBINS + a0.z], 1); atomicAdd(&h[3 * NBINS + a0.w], 1);
        atomicAdd(&h[4 * NBINS + b0.x], 1); atomicAdd(&h[5 * NBINS + b0.y], 1);
        atomicAdd(&h[6 * NBINS + b0.z], 1); atomicAdd(&h[7 * NBINS + b0.w], 1);
        if (i1 < n8) {
            atomicAdd(&h[0 * NBINS + a1.x], 1); atomicAdd(&h[1 * NBINS + a1.y], 1);
            atomicAdd(&h[2 * NBINS + a1.z], 1); atomicAdd(&h[3 * NBINS + a1.w], 1);
            atomicAdd(&h[4 * NBINS + b1.x], 1); atomicAdd(&h[5 * NBINS + b1.y], 1);
            atomicAdd(&h[6 * NBINS + b1.z], 1); atomicAdd(&h[7 * NBINS + b1.w], 1);
        }
        if (i2 < n8) {
            atomicAdd(&h[0 * NBINS + a2.x], 1); atomicAdd(&h[1 * NBINS + a2.y], 1);
            atomicAdd(&h[2 * NBINS + a2.z], 1); atomicAdd(&h[3 * NBINS + a2.w], 1);
            atomicAdd(&h[4 * NBINS + b2.x], 1); atomicAdd(&h[5 * NBINS + b2.y], 1);
            atomicAdd(&h[6 * NBINS + b2.z], 1); atomicAdd(&h[7 * NBINS + b2.w], 1);
        }
        if (i3 < n8) {
            atomicAdd(&h[0 * NBINS + a3.x], 1); atomicAdd(&h[1 * NBINS + a3.y], 1);
            atomicAdd(&h[2 * NBINS + a3.z], 1); atomicAdd(&h[3 * NBINS + a3.w], 1);
            atomicAdd(&h[4 * NBINS + b3.x], 1); atomicAdd(&h[5 * NBINS + b3.y], 1);
            atomicAdd(&h[6 * NBINS + b3.z], 1); atomicAdd(&h[7 * NBINS + b3.w], 1);
        }
    }
    __syncthreads();

    // Flush block-private histogram as packed 64-bit adds (two bins/atomic).
    // Per-bin totals ~4e3 << 2^32 -> no carry across halves. Rotate start
    // offset per block to spread L2 line contention.
    const unsigned long long* __restrict__ h64 = (const unsigned long long*)hist;
    #pragma unroll
    for (int k = 0; k < NQWORDS / THREADS; ++k) {
        const int j = (tid + k * THREADS + blockIdx.x * 32) & (NQWORDS - 1);
        const unsigned long long v = h64[j];
        if (v) atomicAdd(&out[j], v);
    }
}

extern "C" void kernel_launch(void* const* d_in, const int* in_sizes, int n_in,
                              void* d_out, int out_size, void* d_ws, size_t ws_size,
                              hipStream_t stream) {
    const int* in = (const int*)d_in[0];
    unsigned long long* out = (unsigned long long*)d_out;
    const long long n = (long long)in_sizes[0];   // 64,000,000 (divisible by 8)
    const long long n8 = n / 8;

    // Replays accumulate via atomics -> must zero the output every launch.
    hipMemsetAsync(d_out, 0, (size_t)out_size * sizeof(int), stream);

    hist_kernel<<<BLOCKS, THREADS, 0, stream>>>(in, out, n8);
}

// Round 4
// 53.068 us; speedup vs baseline: 1.1010x; 1.1010x over previous
//
#include <hip/hip_runtime.h>

// Per-channel histogram: in [LENGTH=1e6, C=64] int32 values in [0,256),
// out [64, 256] int32 counts. Memory-bound: 256 MB read -> ~41 us floor.
//
// R4: clean MLP experiment. R2 config (256 blocks x 1024 thr, 64 KB LDS,
// packed 64-bit flush) but the main loop has a UNIFORM trip count (no
// per-iter compare) unrolled 2-deep: 4x dwordx4 (64 B/lane) issued before
// any LDS atomic. No launch_bounds VGPR squeeze (R3's mistake).

#define NCH   64
#define NBINS 256
#define HIST_SIZE (NCH * NBINS)   // 16384 ints = 64 KB LDS
#define NQWORDS   (HIST_SIZE / 2) // 8192 packed pairs
#define THREADS 1024
#define BLOCKS  256               // 1 block/CU, 16 waves/CU

__global__ __launch_bounds__(THREADS) void hist_kernel(
    const int* __restrict__ in, unsigned long long* __restrict__ out, long long n8)
{
    __shared__ int hist[HIST_SIZE];
    const int tid = threadIdx.x;

    #pragma unroll
    for (int k = 0; k < HIST_SIZE / THREADS; ++k)
        hist[tid + k * THREADS] = 0;
    __syncthreads();

    const int4* __restrict__ in4 = (const int4*)in;
    const long long stride = (long long)BLOCKS * THREADS;      // divisible by 8
    const long long gid = (long long)blockIdx.x * THREADS + tid;

    // Chunk i covers flat indices [8i,8i+8) -> channels (i&7)*8..+7.
    // stride % 8 == 0 -> channel base is per-thread invariant.
    const int c0 = (int)((gid & 7) << 3);
    int* __restrict__ h = &hist[c0 * NBINS];

    // Uniform trip count: threads gid < rem do one extra chunk at the end.
    const long long full = n8 / stride;          // 30 for the bench shape
    const long long rem  = n8 - full * stride;   // 135680

    long long i = gid;
    long long k = 0;
    for (; k + 2 <= full; k += 2, i += 2 * stride) {
        // Both chunks' loads issued before any dependent LDS atomic.
        int4 a0 = in4[2 * i];            int4 b0 = in4[2 * i + 1];
        int4 a1 = in4[2 * (i + stride)]; int4 b1 = in4[2 * (i + stride) + 1];

        atomicAdd(&h[0 * NBINS + a0.x], 1); atomicAdd(&h[1 * NBINS + a0.y], 1);
        atomicAdd(&h[2 * NBINS + a0.z], 1); atomicAdd(&h[3 * NBINS + a0.w], 1);
        atomicAdd(&h[4 * NBINS + b0.x], 1); atomicAdd(&h[5 * NBINS + b0.y], 1);
        atomicAdd(&h[6 * NBINS + b0.z], 1); atomicAdd(&h[7 * NBINS + b0.w], 1);

        atomicAdd(&h[0 * NBINS + a1.x], 1); atomicAdd(&h[1 * NBINS + a1.y], 1);
        atomicAdd(&h[2 * NBINS + a1.z], 1); atomicAdd(&h[3 * NBINS + a1.w], 1);
        atomicAdd(&h[4 * NBINS + b1.x], 1); atomicAdd(&h[5 * NBINS + b1.y], 1);
        atomicAdd(&h[6 * NBINS + b1.z], 1); atomicAdd(&h[7 * NBINS + b1.w], 1);
    }
    if (k < full) {  // odd 'full' leftover
        int4 a0 = in4[2 * i]; int4 b0 = in4[2 * i + 1];
        atomicAdd(&h[0 * NBINS + a0.x], 1); atomicAdd(&h[1 * NBINS + a0.y], 1);
        atomicAdd(&h[2 * NBINS + a0.z], 1); atomicAdd(&h[3 * NBINS + a0.w], 1);
        atomicAdd(&h[4 * NBINS + b0.x], 1); atomicAdd(&h[5 * NBINS + b0.y], 1);
        atomicAdd(&h[6 * NBINS + b0.z], 1); atomicAdd(&h[7 * NBINS + b0.w], 1);
        i += stride;
    }
    if (gid < rem) {  // tail chunk
        int4 a0 = in4[2 * i]; int4 b0 = in4[2 * i + 1];
        atomicAdd(&h[0 * NBINS + a0.x], 1); atomicAdd(&h[1 * NBINS + a0.y], 1);
        atomicAdd(&h[2 * NBINS + a0.z], 1); atomicAdd(&h[3 * NBINS + a0.w], 1);
        atomicAdd(&h[4 * NBINS + b0.x], 1); atomicAdd(&h[5 * NBINS + b0.y], 1);
        atomicAdd(&h[6 * NBINS + b0.z], 1); atomicAdd(&h[7 * NBINS + b0.w], 1);
    }
    __syncthreads();

    // Flush block-private histogram as packed 64-bit adds (two bins/atomic).
    // Per-bin totals ~4e3 << 2^32 -> no carry across halves. Rotate start
    // offset per block to spread L2 line contention.
    const unsigned long long* __restrict__ h64 = (const unsigned long long*)hist;
    #pragma unroll
    for (int kk = 0; kk < NQWORDS / THREADS; ++kk) {
        const int j = (tid + kk * THREADS + blockIdx.x * 32) & (NQWORDS - 1);
        const unsigned long long v = h64[j];
        if (v) atomicAdd(&out[j], v);
    }
}

extern "C" void kernel_launch(void* const* d_in, const int* in_sizes, int n_in,
                              void* d_out, int out_size, void* d_ws, size_t ws_size,
                              hipStream_t stream) {
    const int* in = (const int*)d_in[0];
    unsigned long long* out = (unsigned long long*)d_out;
    const long long n = (long long)in_sizes[0];   // 64,000,000 (divisible by 8)
    const long long n8 = n / 8;

    // Replays accumulate via atomics -> must zero the output every launch.
    hipMemsetAsync(d_out, 0, (size_t)out_size * sizeof(int), stream);

    hist_kernel<<<BLOCKS, THREADS, 0, stream>>>(in, out, n8);
}